// Round 7
// baseline (507.502 us; speedup 1.0000x reference)
//
#include <hip/hip_runtime.h>
#include <math.h>

// CurvatureLoss via 2D-cell-pruned exact KNN. B=2, N=8192, [B,N,3] fp32.
// Sort each set {tgt, src, warped} into 64x64 (x,y) cells (cell-major order).
// KNN per query: T = K-th smallest of 32 sampled distances (8 lanes x top-4 of a
// 128-pt sorted-order window) -> valid upper bound on final K-th distance;
// scan the cell-rectangle covering ball(q, sqrt(T)), buffer ALL d<=T points
// (each exactly once); exact lex (d, orig_idx) top-K of buffer == reference.
// KNN kernels are __syncthreads-free: all LDS regions are per-query and each
// query's lanes live in one wave (CPQ=8 divides 64) -> program order suffices.

constexpr int BLOCK = 256;
constexpr int NBX = 64, NBY = 64, NCELL = NBX * NBY;
constexpr float XLO = -6.0f, XHI = 6.0f;
constexpr float BKS = NBX / (XHI - XLO);
constexpr int AWIN = 128;          // T-sample window (sorted-order contiguous)
constexpr float RADIUS2 = 2.5f;

__device__ __forceinline__ float sq3(float x, float y, float z) {
    return fmaf(x, x, fmaf(y, y, z * z));
}
// stable ordering (matches jax.lax.top_k tie-break)
__device__ __forceinline__ bool lex_less(float d1, int i1, float d2, int i2) {
    return (d1 < d2) || (d1 == d2 && i1 < i2);
}
// monotone non-decreasing with clamp -> rectangle coverage stays exact
__device__ __forceinline__ int bkt_of(float v) {
    int k = (int)((v - XLO) * BKS);
    return k < 0 ? 0 : (k > NBX - 1 ? NBX - 1 : k);
}

// Cell-sort one (set,b): set 0=tgt, 1=src, 2=warped(src+flow). grid = 6 blocks.
__global__ __launch_bounds__(BLOCK)
void sort_kernel(const float* __restrict__ src, const float* __restrict__ tgt,
                 const float* __restrict__ flow,
                 float4* __restrict__ xyzw, int* __restrict__ sidx,
                 int* __restrict__ bstart, int N)
{
    const int set = blockIdx.x >> 1;
    const int b   = blockIdx.x & 1;
    const size_t pbase = (size_t)b * N * 3;
    const float* P = (set == 0) ? tgt : src;
    const bool addF = (set == 2);
    float4* oxy = xyzw + (size_t)blockIdx.x * N;
    int*    osx = sidx + (size_t)blockIdx.x * N;
    int*    obs = bstart + (size_t)blockIdx.x * (NCELL + 1);

    __shared__ int hist[NCELL];
    __shared__ int tsum[BLOCK];
    const int t = threadIdx.x;
    constexpr int CPT = NCELL / BLOCK;   // 16 cells per thread

    for (int k = t; k < NCELL; k += BLOCK) hist[k] = 0;
    __syncthreads();
    for (int i = t; i < N; i += BLOCK) {
        size_t o = pbase + (size_t)i * 3;
        float x = P[o], y = P[o + 1];
        if (addF) { x += flow[o]; y += flow[o + 1]; }
        atomicAdd(&hist[bkt_of(x) * NBY + bkt_of(y)], 1);
    }
    __syncthreads();
    {   // two-level exclusive scan of hist
        int base = t * CPT, s = 0;
        for (int m = 0; m < CPT; ++m) s += hist[base + m];
        tsum[t] = s;
    }
    __syncthreads();
    if (t == 0) {
        int run = 0;
        for (int u = 0; u < BLOCK; ++u) { int v = tsum[u]; tsum[u] = run; run += v; }
    }
    __syncthreads();
    {
        int base = t * CPT, run = tsum[t];
        for (int m = 0; m < CPT; ++m) {
            int h = hist[base + m];
            hist[base + m] = run;          // cursor
            obs[base + m] = run;           // cell start
            run += h;
        }
    }
    if (t == 0) obs[NCELL] = N;
    __syncthreads();
    for (int i = t; i < N; i += BLOCK) {
        size_t o = pbase + (size_t)i * 3;
        float x = P[o], y = P[o + 1], z = P[o + 2];
        if (addF) { x += flow[o]; y += flow[o + 1]; z += flow[o + 2]; }
        int pos = atomicAdd(&hist[bkt_of(x) * NBY + bkt_of(y)], 1);
        oxy[pos] = make_float4(x, y, z, sq3(x, y, z));
        osx[pos] = i;
    }
}

// KIND 0: self-KNN curvature (mode 0: tgt -> curv2=outA; mode 1: src, gather warped -> moved=outB)
// KIND 1: warped->tgt KNN, interp curv2, subtract moved, loss -> outA
template <int K, int CPQ, int KIND, int CAP>
__global__ __launch_bounds__(BLOCK)
void knn_kernel(const float* __restrict__ src, const float* __restrict__ tgt,
                const float* __restrict__ flow,
                const float4* __restrict__ ws_xyzw, const int* __restrict__ ws_sidx,
                const int* __restrict__ ws_bs,
                const float* __restrict__ curv2, const float* __restrict__ moved,
                float* __restrict__ outA, float* __restrict__ outB,
                int N, float invB)
{
    constexpr int QPB = BLOCK / CPQ;   // 32 queries/block; CPQ=8 divides 64 (wave)
    constexpr int RSZ = CAP;           // per-query pool stride; CAP >= CPQ*K, CPQ*4
    __shared__ float pool_d[QPB * RSZ];
    __shared__ int   pool_i[QPB * RSZ];
    __shared__ int   hcnt[QPB];

    const int tid = threadIdx.x;
    const int ql  = tid / CPQ;
    const int c   = tid % CPQ;
    const int lane = tid & 63;
    const int bpb = N / QPB;

    int blk = blockIdx.x;
    int mode = 0;
    if (KIND == 0) { int half = gridDim.x >> 1; mode = (blk >= half); blk -= mode ? half : 0; }
    const int b  = blk / bpb;
    const int q0 = (blk % bpb) * QPB;
    const size_t bbase = (size_t)b * N * 3;

    const int qset = (KIND == 0) ? mode : 2;
    const int rset = (KIND == 0) ? mode : 0;
    const float4* sQ  = ws_xyzw + (size_t)(qset * 2 + b) * N;
    const int*    sQi = ws_sidx + (size_t)(qset * 2 + b) * N;
    const float4* sRf = ws_xyzw + (size_t)(rset * 2 + b) * N;
    const int*    sRi = ws_sidx + (size_t)(rset * 2 + b) * N;
    const int*    csR = ws_bs   + (size_t)(rset * 2 + b) * (NCELL + 1);

    const int qpos = q0 + ql;
    const float4 q4 = sQ[qpos];
    const int oqi = sQi[qpos];
    const float qx = q4.x, qy = q4.y, qz = q4.z, qq = q4.w;
    const float m2x = -2.0f * qx, m2y = -2.0f * qy, m2z = -2.0f * qz;
    const int qbase = ql * RSZ;

    // ---- T bootstrap: per-lane top-4 distances over a 128-pt local window ----
    int wA0;
    if (KIND == 0) wA0 = qpos - AWIN / 2;
    else           wA0 = csR[bkt_of(qx) * NBY + bkt_of(qy)] - AWIN / 2;
    wA0 = min(max(wA0, 0), N - AWIN);

    float a0 = INFINITY, a1 = INFINITY, a2 = INFINITY, a3 = INFINITY;
#pragma unroll 4
    for (int i = 0; i < AWIN / CPQ; ++i) {
        float4 p = sRf[wA0 + i * CPQ + c];
        float d = fmaf(m2x, p.x, fmaf(m2y, p.y, fmaf(m2z, p.z, qq + p.w)));
        if (d < a3) {
            a3 = d; float tt;
            if (a3 < a2) { tt = a2; a2 = a3; a3 = tt; }
            if (a2 < a1) { tt = a1; a1 = a2; a2 = tt; }
            if (a1 < a0) { tt = a0; a0 = a1; a1 = tt; }
        }
    }
    {   // role a1: per-lane 4 sorted distances
        int o = qbase + c * 4;
        pool_d[o] = a0; pool_d[o + 1] = a1; pool_d[o + 2] = a2; pool_d[o + 3] = a3;
    }
    __builtin_amdgcn_wave_barrier();

    float Tv = 0.0f;
    if (c == 0) {
        hcnt[ql] = 0;
        int pp[CPQ];
#pragma unroll
        for (int cc = 0; cc < CPQ; ++cc) pp[cc] = 0;
        float kth = INFINITY;
#pragma unroll
        for (int k = 0; k < K; ++k) {   // K-th smallest of the 32 samples
            float bdm = INFINITY; int bc = 0;
#pragma unroll
            for (int cc = 0; cc < CPQ; ++cc) {
                float dd = (pp[cc] < 4) ? pool_d[qbase + cc * 4 + pp[cc]] : INFINITY;
                if (dd < bdm) { bdm = dd; bc = cc; }
            }
            kth = bdm;
#pragma unroll
            for (int cc = 0; cc < CPQ; ++cc) pp[cc] += (bc == cc);
        }
        Tv = kth;
    }
    const float T = __shfl(Tv, lane - c);   // broadcast from group leader
    __builtin_amdgcn_wave_barrier();

    // ---- Phase B: scan rectangle of cells covering ball(q, sqrt(T)) ----
    const float s = sqrtf(T);
    const int bxlo = bkt_of(qx - s), bxhi = bkt_of(qx + s);
    const int bylo = bkt_of(qy - s), byhi = bkt_of(qy + s);
    for (int bx = bxlo; bx <= bxhi; ++bx) {
        const int p0 = csR[bx * NBY + bylo];
        const int p1 = csR[bx * NBY + byhi + 1];
        for (int p = p0 + c; p < p1; p += CPQ) {
            float4 pt = sRf[p];
            float d = fmaf(m2x, pt.x, fmaf(m2y, pt.y, fmaf(m2z, pt.z, qq + pt.w)));
            bool hit = d <= T;
            if (__any(hit)) {
                if (hit) {
                    int slot = atomicAdd(&hcnt[ql], 1);
                    if (slot < CAP) {
                        pool_d[qbase + slot] = d;        // role b
                        pool_i[qbase + slot] = sRi[p];
                    }
                }
            }
        }
    }
    __builtin_amdgcn_wave_barrier();

    // ---- Final select: parallel slice-insert + group merge (exact lex top-K) ----
    const int cnt = min(hcnt[ql], CAP);
    float nd[K]; int ni[K];
#pragma unroll
    for (int k = 0; k < K; ++k) { nd[k] = INFINITY; ni[k] = 0x7FFFFFFF; }
    for (int h = c; h < cnt; h += CPQ) {
        float d = pool_d[qbase + h]; int ii = pool_i[qbase + h];
        if (lex_less(d, ii, nd[K - 1], ni[K - 1])) {
            nd[K - 1] = d; ni[K - 1] = ii;
#pragma unroll
            for (int p2 = K - 1; p2 > 0; --p2) {
                if (lex_less(nd[p2], ni[p2], nd[p2 - 1], ni[p2 - 1])) {
                    float td = nd[p2]; nd[p2] = nd[p2 - 1]; nd[p2 - 1] = td;
                    int ti = ni[p2];  ni[p2] = ni[p2 - 1]; ni[p2 - 1] = ti;
                }
            }
        }
    }
    __builtin_amdgcn_wave_barrier();
#pragma unroll
    for (int k = 0; k < K; ++k) {   // role a2: per-lane sorted K-lists
        pool_d[qbase + c * K + k] = nd[k];
        pool_i[qbase + c * K + k] = ni[k];
    }
    __builtin_amdgcn_wave_barrier();

    float sqv = 0.0f;
    if (c == 0) {
        int pp[CPQ];
#pragma unroll
        for (int cc = 0; cc < CPQ; ++cc) pp[cc] = 0;
        float fd[K]; int fi[K];
#pragma unroll
        for (int k = 0; k < K; ++k) {
            float bdm = INFINITY; int bim = 0x7FFFFFFF; int bc = -1;
#pragma unroll
            for (int cc = 0; cc < CPQ; ++cc) {
                float dd = pool_d[qbase + cc * K + pp[cc]];
                int   ii = pool_i[qbase + cc * K + pp[cc]];
                if (lex_less(dd, ii, bdm, bim)) { bdm = dd; bim = ii; bc = cc; }
            }
            fd[k] = bdm; fi[k] = bim;
#pragma unroll
            for (int cc = 0; cc < CPQ; ++cc) pp[cc] += (bc == cc);
        }

        if (KIND == 0) {
            const float* rb   = ((mode == 0) ? tgt : src) + bbase;
            const float* addf = flow + bbase;
            float cx = qx, cy = qy, cz = qz;   // qx.. already includes flow never (mode0/1 raw sets)
            float gx = 0.f, gy = 0.f, gz = 0.f;
            if (mode == 1) {   // center = warped[oqi]
                cx += addf[(size_t)oqi * 3 + 0];
                cy += addf[(size_t)oqi * 3 + 1];
                cz += addf[(size_t)oqi * 3 + 2];
            }
#pragma unroll
            for (int k = 0; k < K; ++k) {
                int j = (fd[k] > RADIUS2) ? fi[0] : fi[k];
                float px = rb[(size_t)j * 3 + 0];
                float py = rb[(size_t)j * 3 + 1];
                float pz = rb[(size_t)j * 3 + 2];
                if (mode == 1) {
                    px += addf[(size_t)j * 3 + 0];
                    py += addf[(size_t)j * 3 + 1];
                    pz += addf[(size_t)j * 3 + 2];
                }
                gx += px - cx; gy += py - cy; gz += pz - cz;
            }
            float* outp = (mode == 0) ? outA : outB;
            outp[bbase + (size_t)oqi * 3 + 0] = gx / 9.0f;
            outp[bbase + (size_t)oqi * 3 + 1] = gy / 9.0f;
            outp[bbase + (size_t)oqi * 3 + 2] = gz / 9.0f;
        } else {
            float w[K]; float wsum = 0.f;
#pragma unroll
            for (int k = 0; k < K; ++k) { w[k] = 1.0f / (fd[k] + 1e-8f); wsum += w[k]; }
            float ix = 0.f, iy = 0.f, iz = 0.f;
#pragma unroll
            for (int k = 0; k < K; ++k) {
                int j = (fd[k] > RADIUS2) ? fi[0] : fi[k];
                float wn = w[k] / wsum;
                ix += wn * curv2[bbase + (size_t)j * 3 + 0];
                iy += wn * curv2[bbase + (size_t)j * 3 + 1];
                iz += wn * curv2[bbase + (size_t)j * 3 + 2];
            }
            float dx = ix - moved[bbase + (size_t)oqi * 3 + 0];
            float dy = iy - moved[bbase + (size_t)oqi * 3 + 1];
            float dz = iz - moved[bbase + (size_t)oqi * 3 + 2];
            sqv = fmaf(dx, dx, fmaf(dy, dy, dz * dz));
        }
    }

    if (KIND == 1) {   // wave-level loss reduction -> one global atomic per wave
        float v = sqv;
#pragma unroll
        for (int sft = 1; sft < 64; sft <<= 1) v += __shfl_xor(v, sft);
        if (lane == 0) atomicAdd(outA, v * invB);
    }
}

extern "C" void kernel_launch(void* const* d_in, const int* in_sizes, int n_in,
                              void* d_out, int out_size, void* d_ws, size_t ws_size,
                              hipStream_t stream) {
    const float* src  = (const float*)d_in[0];
    const float* tgt  = (const float*)d_in[1];
    const float* flow = (const float*)d_in[2];
    float* out = (float*)d_out;

    const int B = 2;
    const int N = in_sizes[0] / (B * 3);        // 8192

    float*  curv2  = (float*)d_ws;                         // B*N*3 f32
    float*  moved  = curv2 + (size_t)B * N * 3;            // B*N*3 f32
    float4* xyzw   = (float4*)(moved + (size_t)B * N * 3); // 6*N float4
    int*    sidx   = (int*)(xyzw + (size_t)6 * N);         // 6*N int
    int*    bstart = sidx + (size_t)6 * N;                 // 6*(NCELL+1) int

    hipMemsetAsync(d_out, 0, sizeof(float), stream);

    sort_kernel<<<6, BLOCK, 0, stream>>>(src, tgt, flow, xyzw, sidx, bstart, N);

    // fused self-KNN curvatures: grid = 2 modes * B * N/32 = 1024 blocks
    knn_kernel<10, 8, 0, 96><<<2 * B * (N / 32), BLOCK, 0, stream>>>(
        src, tgt, flow, xyzw, sidx, bstart, nullptr, nullptr, curv2, moved, N, 0.f);

    // interp + loss: grid = B * N/32 = 512 blocks
    knn_kernel<5, 8, 1, 96><<<B * (N / 32), BLOCK, 0, stream>>>(
        src, tgt, flow, xyzw, sidx, bstart, curv2, moved, out, nullptr, N, 1.0f / B);
}

// Round 8
// 480.435 us; speedup vs baseline: 1.0563x; 1.0563x over previous
//
#include <hip/hip_runtime.h>
#include <math.h>

// CurvatureLoss via 2D-cell-pruned exact KNN. B=2, N=8192, [B,N,3] fp32.
// sort: each set {tgt, src, warped=src+flow} into 64x64 (x,y) cells, cell-major.
// knn per query q:
//   phase A: block stages the 256 cell-contiguous points around its query run
//     (2D-local); each of q's CPQ=8 lanes keeps float-only top-4 of its 32
//     candidates; c==0 merges pooled 32 -> T = K-th smallest. T >= true K-th
//     distance (order-statistics argument), and is near-tight (pooled from all
//     256 evaluated distances).
//   phase B: scan the cell-rectangle covering ball(q, sqrt(T)) (cols
//     [qx+-sqrt(T)] x y-band [qy+-sqrt(T)]); buffer ALL d<=T points, each
//     exactly once (no seeding, no dedup). >=K guaranteed.
//   final: exact lex (d, orig_idx) top-K of buffer == jax.lax.top_k result.
// Epilogue formulas byte-identical to rounds 2-6 (absmax 0.0 proven).

constexpr int BLOCK = 256;
constexpr int NBX = 64, NBY = 64, NCELL = NBX * NBY;
constexpr float XLO = -6.0f, XHI = 6.0f;
constexpr float BKS = NBX / (XHI - XLO);
constexpr int AWIN = 256;          // phase-A window == BLOCK (1 pt/thread stage)
constexpr float RADIUS2 = 2.5f;

__device__ __forceinline__ float sq3(float x, float y, float z) {
    return fmaf(x, x, fmaf(y, y, z * z));
}
// stable ordering (matches jax.lax.top_k tie-break)
__device__ __forceinline__ bool lex_less(float d1, int i1, float d2, int i2) {
    return (d1 < d2) || (d1 == d2 && i1 < i2);
}
// monotone non-decreasing with clamp -> rectangle coverage stays exact
__device__ __forceinline__ int bkt_of(float v) {
    int k = (int)((v - XLO) * BKS);
    return k < 0 ? 0 : (k > NBX - 1 ? NBX - 1 : k);
}

// Cell-sort one (set,b): set 0=tgt, 1=src, 2=warped(src+flow). grid = 6 blocks.
__global__ __launch_bounds__(BLOCK)
void sort_kernel(const float* __restrict__ src, const float* __restrict__ tgt,
                 const float* __restrict__ flow,
                 float4* __restrict__ xyzw, int* __restrict__ sidx,
                 int* __restrict__ bstart, int N)
{
    const int set = blockIdx.x >> 1;
    const int b   = blockIdx.x & 1;
    const size_t pbase = (size_t)b * N * 3;
    const float* P = (set == 0) ? tgt : src;
    const bool addF = (set == 2);
    float4* oxy = xyzw + (size_t)blockIdx.x * N;
    int*    osx = sidx + (size_t)blockIdx.x * N;
    int*    obs = bstart + (size_t)blockIdx.x * (NCELL + 1);

    __shared__ int hist[NCELL];
    __shared__ int tsum[BLOCK];
    const int t = threadIdx.x;
    constexpr int CPT = NCELL / BLOCK;   // 16 cells per thread

    for (int k = t; k < NCELL; k += BLOCK) hist[k] = 0;
    __syncthreads();
    for (int i = t; i < N; i += BLOCK) {
        size_t o = pbase + (size_t)i * 3;
        float x = P[o], y = P[o + 1];
        if (addF) { x += flow[o]; y += flow[o + 1]; }
        atomicAdd(&hist[bkt_of(x) * NBY + bkt_of(y)], 1);
    }
    __syncthreads();
    {   // two-level exclusive scan
        int base = t * CPT, s = 0;
        for (int m = 0; m < CPT; ++m) s += hist[base + m];
        tsum[t] = s;
    }
    __syncthreads();
    if (t == 0) {
        int run = 0;
        for (int u = 0; u < BLOCK; ++u) { int v = tsum[u]; tsum[u] = run; run += v; }
    }
    __syncthreads();
    {
        int base = t * CPT, run = tsum[t];
        for (int m = 0; m < CPT; ++m) {
            int h = hist[base + m];
            hist[base + m] = run;          // scatter cursor
            obs[base + m] = run;           // cell start
            run += h;
        }
    }
    if (t == 0) obs[NCELL] = N;
    __syncthreads();
    for (int i = t; i < N; i += BLOCK) {
        size_t o = pbase + (size_t)i * 3;
        float x = P[o], y = P[o + 1], z = P[o + 2];
        if (addF) { x += flow[o]; y += flow[o + 1]; z += flow[o + 2]; }
        int pos = atomicAdd(&hist[bkt_of(x) * NBY + bkt_of(y)], 1);
        oxy[pos] = make_float4(x, y, z, sq3(x, y, z));
        osx[pos] = i;
    }
}

// KIND 0: self-KNN curvature (mode 0: tgt -> curv2=outA; mode 1: src, gather warped -> moved=outB)
// KIND 1: warped->tgt KNN, interp curv2, subtract moved, loss -> outA
template <int K, int CPQ, int KIND, int CAP>
__global__ __launch_bounds__(BLOCK)
void knn_kernel(const float* __restrict__ src, const float* __restrict__ tgt,
                const float* __restrict__ flow,
                const float4* __restrict__ ws_xyzw, const int* __restrict__ ws_sidx,
                const int* __restrict__ ws_bs,
                const float* __restrict__ curv2, const float* __restrict__ moved,
                float* __restrict__ outA, float* __restrict__ outB,
                int N, float invB)
{
    constexpr int QPB = BLOCK / CPQ;   // 32 queries/block
    // pool roles (barrier-separated lifetimes), per query stride CAP:
    //   a1: per-lane sorted top-4 distances   [CPQ*4  <= CAP]
    //   b : hit buffer (d, idx)               [CAP]
    //   a2: per-lane sorted K-lists           [CPQ*K  <= CAP]
    static_assert(CPQ * 4 <= CAP && CPQ * K <= CAP, "CAP too small");
    __shared__ float4 swin[AWIN];
    __shared__ float  pool_d[QPB * CAP];
    __shared__ int    pool_i[QPB * CAP];
    __shared__ float  Tsh[QPB];
    __shared__ int    hcnt[QPB];
    __shared__ float  lsum;

    const int tid = threadIdx.x;
    const int ql  = tid / CPQ;
    const int c   = tid % CPQ;
    const int bpb = N / QPB;

    int blk = blockIdx.x;
    int mode = 0;
    if (KIND == 0) { int half = gridDim.x >> 1; mode = (blk >= half); blk -= mode ? half : 0; }
    const int b  = blk / bpb;
    const int q0 = (blk % bpb) * QPB;
    const size_t bbase = (size_t)b * N * 3;

    const int qset = (KIND == 0) ? mode : 2;
    const int rset = (KIND == 0) ? mode : 0;
    const float4* sQ  = ws_xyzw + (size_t)(qset * 2 + b) * N;
    const int*    sQi = ws_sidx + (size_t)(qset * 2 + b) * N;
    const float4* sRf = ws_xyzw + (size_t)(rset * 2 + b) * N;
    const int*    sRi = ws_sidx + (size_t)(rset * 2 + b) * N;
    const int*    csR = ws_bs   + (size_t)(rset * 2 + b) * (NCELL + 1);

    const int qpos = q0 + ql;
    const float4 q4 = sQ[qpos];
    const int oqi = sQi[qpos];
    const float qx = q4.x, qy = q4.y, qz = q4.z, qq = q4.w;
    const float m2x = -2.0f * qx, m2y = -2.0f * qy, m2z = -2.0f * qz;
    const int qbase = ql * CAP;

    // ---- phase A: stage 2D-local window (block-uniform), per-lane top-4 ----
    int wA0;
    if (KIND == 0) {
        wA0 = q0 + QPB / 2 - AWIN / 2;
    } else {
        float4 mq = sQ[q0 + QPB / 2];
        wA0 = csR[bkt_of(mq.x) * NBY + bkt_of(mq.y)] - AWIN / 2;
    }
    wA0 = min(max(wA0, 0), N - AWIN);

    swin[tid] = sRf[wA0 + tid];
    if (tid == 0) lsum = 0.0f;
    __syncthreads();

    float a0 = INFINITY, a1 = INFINITY, a2 = INFINITY, a3 = INFINITY;
#pragma unroll 8
    for (int i = 0; i < AWIN / CPQ; ++i) {
        float4 p = swin[i * CPQ + c];
        float d = fmaf(m2x, p.x, fmaf(m2y, p.y, fmaf(m2z, p.z, qq + p.w)));
        if (d < a3) {
            a3 = d; float tt;
            if (a3 < a2) { tt = a2; a2 = a3; a3 = tt; }
            if (a2 < a1) { tt = a1; a1 = a2; a2 = tt; }
            if (a1 < a0) { tt = a0; a0 = a1; a1 = tt; }
        }
    }
    {   // role a1
        int o = qbase + c * 4;
        pool_d[o] = a0; pool_d[o + 1] = a1; pool_d[o + 2] = a2; pool_d[o + 3] = a3;
    }
    if (c == 0) hcnt[ql] = 0;
    __syncthreads();

    if (c == 0) {   // T = K-th smallest of pooled 32 (valid upper bound, near-tight)
        int pp[CPQ];
#pragma unroll
        for (int cc = 0; cc < CPQ; ++cc) pp[cc] = 0;
        float kth = INFINITY;
#pragma unroll
        for (int k = 0; k < K; ++k) {
            float bdm = INFINITY; int bc = 0;
#pragma unroll
            for (int cc = 0; cc < CPQ; ++cc) {
                float dd = (pp[cc] < 4) ? pool_d[qbase + cc * 4 + pp[cc]] : INFINITY;
                if (dd < bdm) { bdm = dd; bc = cc; }
            }
            kth = bdm;
#pragma unroll
            for (int cc = 0; cc < CPQ; ++cc) pp[cc] += (bc == cc);
        }
        Tsh[ql] = kth;
    }
    __syncthreads();
    const float T = Tsh[ql];

    // ---- phase B: scan ball rectangle, buffer ALL d<=T (each point once) ----
    const float s = sqrtf(T);
    const int bxlo = bkt_of(qx - s), bxhi = bkt_of(qx + s);
    const int bylo = bkt_of(qy - s), byhi = bkt_of(qy + s);
    for (int bx = bxlo; bx <= bxhi; ++bx) {
        int p0 = csR[bx * NBY + bylo];
        int p1 = csR[bx * NBY + byhi + 1];
        p0 = max(p0, 0); p1 = min(p1, N);   // bounded even w/ stale ws (replay)
        for (int p = p0 + c; p < p1; p += CPQ) {
            float4 pt = sRf[p];
            float d = fmaf(m2x, pt.x, fmaf(m2y, pt.y, fmaf(m2z, pt.z, qq + pt.w)));
            if (d <= T) {
                int slot = atomicAdd(&hcnt[ql], 1);
                if (slot < CAP) {
                    pool_d[qbase + slot] = d;     // role b
                    pool_i[qbase + slot] = sRi[p];
                }
            }
        }
    }
    __syncthreads();

    // ---- final select: per-lane strided K-insert, then c==0 CPQ-way merge ----
    const int cnt = min(hcnt[ql], CAP);
    float nd[K]; int ni[K];
#pragma unroll
    for (int k = 0; k < K; ++k) { nd[k] = INFINITY; ni[k] = 0x7FFFFFFF; }
    for (int h = c; h < cnt; h += CPQ) {
        float d = pool_d[qbase + h]; int ii = pool_i[qbase + h];
        if (lex_less(d, ii, nd[K - 1], ni[K - 1])) {
            nd[K - 1] = d; ni[K - 1] = ii;
#pragma unroll
            for (int p2 = K - 1; p2 > 0; --p2) {
                if (lex_less(nd[p2], ni[p2], nd[p2 - 1], ni[p2 - 1])) {
                    float td = nd[p2]; nd[p2] = nd[p2 - 1]; nd[p2 - 1] = td;
                    int ti = ni[p2];  ni[p2] = ni[p2 - 1]; ni[p2 - 1] = ti;
                }
            }
        }
    }
    __syncthreads();   // hits consumed
#pragma unroll
    for (int k = 0; k < K; ++k) {   // role a2
        pool_d[qbase + c * K + k] = nd[k];
        pool_i[qbase + c * K + k] = ni[k];
    }
    __syncthreads();

    if (c == 0) {
        int pp[CPQ];
#pragma unroll
        for (int cc = 0; cc < CPQ; ++cc) pp[cc] = 0;
        float fd[K]; int fi[K];
#pragma unroll
        for (int k = 0; k < K; ++k) {
            float bdm = INFINITY; int bim = 0x7FFFFFFF; int bc = -1;
#pragma unroll
            for (int cc = 0; cc < CPQ; ++cc) {
                float dd = pool_d[qbase + cc * K + pp[cc]];
                int   ii = pool_i[qbase + cc * K + pp[cc]];
                if (lex_less(dd, ii, bdm, bim)) { bdm = dd; bim = ii; bc = cc; }
            }
            fd[k] = bdm; fi[k] = bim;
#pragma unroll
            for (int cc = 0; cc < CPQ; ++cc) pp[cc] += (bc == cc);
        }

        if (KIND == 0) {
            const float* rb   = ((mode == 0) ? tgt : src) + bbase;
            const float* addf = flow + bbase;
            float cx = qx, cy = qy, cz = qz;
            float gx = 0.f, gy = 0.f, gz = 0.f;
            if (mode == 1) {   // center = warped[oqi]
                cx += addf[(size_t)oqi * 3 + 0];
                cy += addf[(size_t)oqi * 3 + 1];
                cz += addf[(size_t)oqi * 3 + 2];
            }
#pragma unroll
            for (int k = 0; k < K; ++k) {
                int j = (fd[k] > RADIUS2) ? fi[0] : fi[k];
                float px = rb[(size_t)j * 3 + 0];
                float py = rb[(size_t)j * 3 + 1];
                float pz = rb[(size_t)j * 3 + 2];
                if (mode == 1) {
                    px += addf[(size_t)j * 3 + 0];
                    py += addf[(size_t)j * 3 + 1];
                    pz += addf[(size_t)j * 3 + 2];
                }
                gx += px - cx; gy += py - cy; gz += pz - cz;
            }
            float* outp = (mode == 0) ? outA : outB;
            outp[bbase + (size_t)oqi * 3 + 0] = gx / 9.0f;
            outp[bbase + (size_t)oqi * 3 + 1] = gy / 9.0f;
            outp[bbase + (size_t)oqi * 3 + 2] = gz / 9.0f;
        } else {
            float w[K]; float wsum = 0.f;
#pragma unroll
            for (int k = 0; k < K; ++k) { w[k] = 1.0f / (fd[k] + 1e-8f); wsum += w[k]; }
            float ix = 0.f, iy = 0.f, iz = 0.f;
#pragma unroll
            for (int k = 0; k < K; ++k) {
                int j = (fd[k] > RADIUS2) ? fi[0] : fi[k];
                float wn = w[k] / wsum;
                ix += wn * curv2[bbase + (size_t)j * 3 + 0];
                iy += wn * curv2[bbase + (size_t)j * 3 + 1];
                iz += wn * curv2[bbase + (size_t)j * 3 + 2];
            }
            float dx = ix - moved[bbase + (size_t)oqi * 3 + 0];
            float dy = iy - moved[bbase + (size_t)oqi * 3 + 1];
            float dz = iz - moved[bbase + (size_t)oqi * 3 + 2];
            float sqv = fmaf(dx, dx, fmaf(dy, dy, dz * dz));
            atomicAdd(&lsum, sqv);
        }
    }

    if (KIND == 1) {
        __syncthreads();
        if (tid == 0) atomicAdd(outA, lsum * invB);
    }
}

extern "C" void kernel_launch(void* const* d_in, const int* in_sizes, int n_in,
                              void* d_out, int out_size, void* d_ws, size_t ws_size,
                              hipStream_t stream) {
    const float* src  = (const float*)d_in[0];
    const float* tgt  = (const float*)d_in[1];
    const float* flow = (const float*)d_in[2];
    float* out = (float*)d_out;

    const int B = 2;
    const int N = in_sizes[0] / (B * 3);        // 8192

    float*  curv2  = (float*)d_ws;                         // B*N*3 f32
    float*  moved  = curv2 + (size_t)B * N * 3;            // B*N*3 f32
    float4* xyzw   = (float4*)(moved + (size_t)B * N * 3); // 6*N float4
    int*    sidx   = (int*)(xyzw + (size_t)6 * N);         // 6*N int
    int*    bstart = sidx + (size_t)6 * N;                 // 6*(NCELL+1) int

    hipMemsetAsync(d_out, 0, sizeof(float), stream);

    sort_kernel<<<6, BLOCK, 0, stream>>>(src, tgt, flow, xyzw, sidx, bstart, N);

    // fused self-KNN curvatures: grid = 2 modes * B * N/32 = 1024 blocks
    knn_kernel<10, 8, 0, 96><<<2 * B * (N / 32), BLOCK, 0, stream>>>(
        src, tgt, flow, xyzw, sidx, bstart, nullptr, nullptr, curv2, moved, N, 0.f);

    // interp + loss: grid = B * N/32 = 512 blocks
    knn_kernel<5, 8, 1, 96><<<B * (N / 32), BLOCK, 0, stream>>>(
        src, tgt, flow, xyzw, sidx, bstart, curv2, moved, out, nullptr, N, 1.0f / B);
}

// Round 9
// 318.721 us; speedup vs baseline: 1.5923x; 1.5074x over previous
//
#include <hip/hip_runtime.h>
#include <math.h>

// CurvatureLoss via 2D-cell-pruned exact KNN. B=2, N=8192, [B,N,3] fp32.
// sort: each set {tgt, src, warped=src+flow} into 64x64 (x,y) cells, cell-major.
// knn per query q (8 lanes of ONE wave per query; no block-wide sync):
//   phase A: 128 cell-contiguous points centered on q's OWN slot/cell (2D-local);
//     per-lane float top-4 (16 fully-unrolled independent loads); group leader
//     merges pooled 32 -> T = K-th smallest (>= true K-th distance: subset
//     order statistic; near-tight because window is 2D-local to q).
//   phase B: scan cell-rectangle covering ball(q, sqrt(T)); buffer ALL d<=T
//     points exactly once (4-way unrolled loads). >=K guaranteed.
//   final: exact lex (d, orig_idx) top-K of buffer == jax.lax.top_k result.
// Deterministic: candidate set {d<=T} ⊇ true top-K for ANY valid T, and lex
// keys are unique -> output independent of scatter order (CAP never binding
// with tight T; 4-6x margin).

constexpr int BLOCK = 256;
constexpr int NBX = 64, NBY = 64, NCELL = NBX * NBY;
constexpr float XLO = -6.0f, XHI = 6.0f;
constexpr float BKS = NBX / (XHI - XLO);
constexpr int AWIN = 128;          // per-query T-sample window
constexpr float RADIUS2 = 2.5f;

__device__ __forceinline__ float sq3(float x, float y, float z) {
    return fmaf(x, x, fmaf(y, y, z * z));
}
// stable ordering (matches jax.lax.top_k tie-break)
__device__ __forceinline__ bool lex_less(float d1, int i1, float d2, int i2) {
    return (d1 < d2) || (d1 == d2 && i1 < i2);
}
// monotone non-decreasing with clamp -> rectangle coverage stays exact
__device__ __forceinline__ int bkt_of(float v) {
    int k = (int)((v - XLO) * BKS);
    return k < 0 ? 0 : (k > NBX - 1 ? NBX - 1 : k);
}

// Cell-sort one (set,b): set 0=tgt, 1=src, 2=warped(src+flow). grid = 6 blocks.
__global__ __launch_bounds__(BLOCK)
void sort_kernel(const float* __restrict__ src, const float* __restrict__ tgt,
                 const float* __restrict__ flow,
                 float4* __restrict__ xyzw, int* __restrict__ sidx,
                 int* __restrict__ bstart, int N)
{
    const int set = blockIdx.x >> 1;
    const int b   = blockIdx.x & 1;
    const size_t pbase = (size_t)b * N * 3;
    const float* P = (set == 0) ? tgt : src;
    const bool addF = (set == 2);
    float4* oxy = xyzw + (size_t)blockIdx.x * N;
    int*    osx = sidx + (size_t)blockIdx.x * N;
    int*    obs = bstart + (size_t)blockIdx.x * (NCELL + 1);

    __shared__ int hist[NCELL];
    __shared__ int tsum[BLOCK];
    const int t = threadIdx.x;
    constexpr int CPT = NCELL / BLOCK;   // 16 cells per thread

    for (int k = t; k < NCELL; k += BLOCK) hist[k] = 0;
    __syncthreads();
    for (int i = t; i < N; i += BLOCK) {
        size_t o = pbase + (size_t)i * 3;
        float x = P[o], y = P[o + 1];
        if (addF) { x += flow[o]; y += flow[o + 1]; }
        atomicAdd(&hist[bkt_of(x) * NBY + bkt_of(y)], 1);
    }
    __syncthreads();
    {   // two-level exclusive scan
        int base = t * CPT, s = 0;
        for (int m = 0; m < CPT; ++m) s += hist[base + m];
        tsum[t] = s;
    }
    __syncthreads();
    if (t == 0) {
        int run = 0;
        for (int u = 0; u < BLOCK; ++u) { int v = tsum[u]; tsum[u] = run; run += v; }
    }
    __syncthreads();
    {
        int base = t * CPT, run = tsum[t];
        for (int m = 0; m < CPT; ++m) {
            int h = hist[base + m];
            hist[base + m] = run;          // scatter cursor
            obs[base + m] = run;           // cell start
            run += h;
        }
    }
    if (t == 0) obs[NCELL] = N;
    __syncthreads();
    for (int i = t; i < N; i += BLOCK) {
        size_t o = pbase + (size_t)i * 3;
        float x = P[o], y = P[o + 1], z = P[o + 2];
        if (addF) { x += flow[o]; y += flow[o + 1]; z += flow[o + 2]; }
        int pos = atomicAdd(&hist[bkt_of(x) * NBY + bkt_of(y)], 1);
        oxy[pos] = make_float4(x, y, z, sq3(x, y, z));
        osx[pos] = i;
    }
}

// KIND 0: self-KNN curvature (mode 0: tgt -> curv2=outA; mode 1: src, gather warped -> moved=outB)
// KIND 1: warped->tgt KNN, interp curv2, subtract moved, loss -> outA
template <int K, int CPQ, int KIND, int CAP>
__global__ __launch_bounds__(BLOCK)
void knn_kernel(const float* __restrict__ src, const float* __restrict__ tgt,
                const float* __restrict__ flow,
                const float4* __restrict__ ws_xyzw, const int* __restrict__ ws_sidx,
                const int* __restrict__ ws_bs,
                const float* __restrict__ curv2, const float* __restrict__ moved,
                float* __restrict__ outA, float* __restrict__ outB,
                int N, float invB)
{
    constexpr int QPB = BLOCK / CPQ;   // 32 queries/block; CPQ=8 lanes = 1 query
    // pool roles per query (stride CAP), lifetimes sequenced by same-wave order:
    //   a1: per-lane sorted top-4 distances [CPQ*4], b: hit buffer [CAP],
    //   a2: per-lane sorted K-lists [CPQ*K]
    static_assert(CPQ * 4 <= CAP && CPQ * K <= CAP, "CAP too small");
    __shared__ float pool_d[QPB * CAP];
    __shared__ int   pool_i[QPB * CAP];
    __shared__ int   hcnt[QPB];

    const int tid  = threadIdx.x;
    const int ql   = tid / CPQ;
    const int c    = tid % CPQ;
    const int lane = tid & 63;
    const int bpb  = N / QPB;

    int blk = blockIdx.x;
    int mode = 0;
    if (KIND == 0) { int half = gridDim.x >> 1; mode = (blk >= half); blk -= mode ? half : 0; }
    const int b  = blk / bpb;
    const int q0 = (blk % bpb) * QPB;
    const size_t bbase = (size_t)b * N * 3;

    const int qset = (KIND == 0) ? mode : 2;
    const int rset = (KIND == 0) ? mode : 0;
    const float4* sQ  = ws_xyzw + (size_t)(qset * 2 + b) * N;
    const int*    sQi = ws_sidx + (size_t)(qset * 2 + b) * N;
    const float4* sRf = ws_xyzw + (size_t)(rset * 2 + b) * N;
    const int*    sRi = ws_sidx + (size_t)(rset * 2 + b) * N;
    const int*    csR = ws_bs   + (size_t)(rset * 2 + b) * (NCELL + 1);

    const int qpos = q0 + ql;
    const float4 q4 = sQ[qpos];
    const int oqi = sQi[qpos];
    const float qx = q4.x, qy = q4.y, qz = q4.z, qq = q4.w;
    const float m2x = -2.0f * qx, m2y = -2.0f * qy, m2z = -2.0f * qz;
    const int qbase = ql * CAP;

    if (c == 0) hcnt[ql] = 0;

    // ---- phase A: per-query 2D-local window, per-lane float top-4 ----
    int wq;
    if (KIND == 0) {
        wq = qpos - AWIN / 2;            // own slot: cell-major locality
    } else {
        wq = csR[bkt_of(qx) * NBY + bkt_of(qy)] - AWIN / 2;  // own cell start
    }
    wq = min(max(wq, 0), N - AWIN);

    float a0 = INFINITY, a1 = INFINITY, a2 = INFINITY, a3 = INFINITY;
#pragma unroll
    for (int i = 0; i < AWIN / CPQ; ++i) {   // 16 independent loads -> 1 epoch
        float4 p = sRf[wq + i * CPQ + c];
        float d = fmaf(m2x, p.x, fmaf(m2y, p.y, fmaf(m2z, p.z, qq + p.w)));
        if (d < a3) {
            a3 = d; float tt;
            if (a3 < a2) { tt = a2; a2 = a3; a3 = tt; }
            if (a2 < a1) { tt = a1; a1 = a2; a2 = tt; }
            if (a1 < a0) { tt = a0; a0 = a1; a1 = tt; }
        }
    }
    {   // role a1
        int o = qbase + c * 4;
        pool_d[o] = a0; pool_d[o + 1] = a1; pool_d[o + 2] = a2; pool_d[o + 3] = a3;
    }
    __builtin_amdgcn_wave_barrier();

    float Tv = 0.0f;
    if (c == 0) {   // T = K-th smallest of pooled 32 (valid upper bound, tight)
        int pp[CPQ];
#pragma unroll
        for (int cc = 0; cc < CPQ; ++cc) pp[cc] = 0;
        float kth = INFINITY;
#pragma unroll
        for (int k = 0; k < K; ++k) {
            float bdm = INFINITY; int bc = 0;
#pragma unroll
            for (int cc = 0; cc < CPQ; ++cc) {
                float dd = (pp[cc] < 4) ? pool_d[qbase + cc * 4 + pp[cc]] : INFINITY;
                if (dd < bdm) { bdm = dd; bc = cc; }
            }
            kth = bdm;
#pragma unroll
            for (int cc = 0; cc < CPQ; ++cc) pp[cc] += (bc == cc);
        }
        Tv = kth;
    }
    const float T = __shfl(Tv, lane - c);   // broadcast from group leader
    __builtin_amdgcn_wave_barrier();

    // ---- phase B: scan ball rectangle, buffer ALL d<=T (each point once) ----
    const float s = sqrtf(T);
    const int bxlo = bkt_of(qx - s), bxhi = bkt_of(qx + s);
    const int bylo = bkt_of(qy - s), byhi = bkt_of(qy + s);
    for (int bx = bxlo; bx <= bxhi; ++bx) {
        int p0 = max(csR[bx * NBY + bylo], 0);
        int p1 = min(csR[bx * NBY + byhi + 1], N);   // bounded even w/ stale ws
        for (int p = p0 + c; p < p1; p += 4 * CPQ) {
            const int i1 = p + CPQ, i2 = p + 2 * CPQ, i3 = p + 3 * CPQ;
            const int e = p1 - 1;
            float4 t0 = sRf[p];
            float4 t1 = sRf[min(i1, e)];
            float4 t2 = sRf[min(i2, e)];
            float4 t3 = sRf[min(i3, e)];
            float d0 = fmaf(m2x, t0.x, fmaf(m2y, t0.y, fmaf(m2z, t0.z, qq + t0.w)));
            float d1 = fmaf(m2x, t1.x, fmaf(m2y, t1.y, fmaf(m2z, t1.z, qq + t1.w)));
            float d2 = fmaf(m2x, t2.x, fmaf(m2y, t2.y, fmaf(m2z, t2.z, qq + t2.w)));
            float d3 = fmaf(m2x, t3.x, fmaf(m2y, t3.y, fmaf(m2z, t3.z, qq + t3.w)));
            if (d0 <= T) {
                int slot = atomicAdd(&hcnt[ql], 1);
                if (slot < CAP) { pool_d[qbase + slot] = d0; pool_i[qbase + slot] = sRi[p]; }
            }
            if (i1 < p1 && d1 <= T) {
                int slot = atomicAdd(&hcnt[ql], 1);
                if (slot < CAP) { pool_d[qbase + slot] = d1; pool_i[qbase + slot] = sRi[i1]; }
            }
            if (i2 < p1 && d2 <= T) {
                int slot = atomicAdd(&hcnt[ql], 1);
                if (slot < CAP) { pool_d[qbase + slot] = d2; pool_i[qbase + slot] = sRi[i2]; }
            }
            if (i3 < p1 && d3 <= T) {
                int slot = atomicAdd(&hcnt[ql], 1);
                if (slot < CAP) { pool_d[qbase + slot] = d3; pool_i[qbase + slot] = sRi[i3]; }
            }
        }
    }
    __builtin_amdgcn_wave_barrier();

    // ---- final select: per-lane strided K-insert, then leader CPQ-way merge ----
    const int cnt = min(hcnt[ql], CAP);
    float nd[K]; int ni[K];
#pragma unroll
    for (int k = 0; k < K; ++k) { nd[k] = INFINITY; ni[k] = 0x7FFFFFFF; }
    for (int h = c; h < cnt; h += CPQ) {
        float d = pool_d[qbase + h]; int ii = pool_i[qbase + h];
        if (lex_less(d, ii, nd[K - 1], ni[K - 1])) {
            nd[K - 1] = d; ni[K - 1] = ii;
#pragma unroll
            for (int p2 = K - 1; p2 > 0; --p2) {
                if (lex_less(nd[p2], ni[p2], nd[p2 - 1], ni[p2 - 1])) {
                    float td = nd[p2]; nd[p2] = nd[p2 - 1]; nd[p2 - 1] = td;
                    int ti = ni[p2];  ni[p2] = ni[p2 - 1]; ni[p2 - 1] = ti;
                }
            }
        }
    }
    __builtin_amdgcn_wave_barrier();
#pragma unroll
    for (int k = 0; k < K; ++k) {   // role a2
        pool_d[qbase + c * K + k] = nd[k];
        pool_i[qbase + c * K + k] = ni[k];
    }
    __builtin_amdgcn_wave_barrier();

    float sqv = 0.0f;
    if (c == 0) {
        int pp[CPQ];
#pragma unroll
        for (int cc = 0; cc < CPQ; ++cc) pp[cc] = 0;
        float fd[K]; int fi[K];
#pragma unroll
        for (int k = 0; k < K; ++k) {
            float bdm = INFINITY; int bim = 0x7FFFFFFF; int bc = -1;
#pragma unroll
            for (int cc = 0; cc < CPQ; ++cc) {
                float dd = pool_d[qbase + cc * K + pp[cc]];
                int   ii = pool_i[qbase + cc * K + pp[cc]];
                if (lex_less(dd, ii, bdm, bim)) { bdm = dd; bim = ii; bc = cc; }
            }
            fd[k] = bdm; fi[k] = bim;
#pragma unroll
            for (int cc = 0; cc < CPQ; ++cc) pp[cc] += (bc == cc);
        }

        if (KIND == 0) {
            const float* rb   = ((mode == 0) ? tgt : src) + bbase;
            const float* addf = flow + bbase;
            float cx = qx, cy = qy, cz = qz;
            float gx = 0.f, gy = 0.f, gz = 0.f;
            if (mode == 1) {   // center = warped[oqi]
                cx += addf[(size_t)oqi * 3 + 0];
                cy += addf[(size_t)oqi * 3 + 1];
                cz += addf[(size_t)oqi * 3 + 2];
            }
#pragma unroll
            for (int k = 0; k < K; ++k) {
                int j = (fd[k] > RADIUS2) ? fi[0] : fi[k];
                float px = rb[(size_t)j * 3 + 0];
                float py = rb[(size_t)j * 3 + 1];
                float pz = rb[(size_t)j * 3 + 2];
                if (mode == 1) {
                    px += addf[(size_t)j * 3 + 0];
                    py += addf[(size_t)j * 3 + 1];
                    pz += addf[(size_t)j * 3 + 2];
                }
                gx += px - cx; gy += py - cy; gz += pz - cz;
            }
            float* outp = (mode == 0) ? outA : outB;
            outp[bbase + (size_t)oqi * 3 + 0] = gx / 9.0f;
            outp[bbase + (size_t)oqi * 3 + 1] = gy / 9.0f;
            outp[bbase + (size_t)oqi * 3 + 2] = gz / 9.0f;
        } else {
            float w[K]; float wsum = 0.f;
#pragma unroll
            for (int k = 0; k < K; ++k) { w[k] = 1.0f / (fd[k] + 1e-8f); wsum += w[k]; }
            float ix = 0.f, iy = 0.f, iz = 0.f;
#pragma unroll
            for (int k = 0; k < K; ++k) {
                int j = (fd[k] > RADIUS2) ? fi[0] : fi[k];
                float wn = w[k] / wsum;
                ix += wn * curv2[bbase + (size_t)j * 3 + 0];
                iy += wn * curv2[bbase + (size_t)j * 3 + 1];
                iz += wn * curv2[bbase + (size_t)j * 3 + 2];
            }
            float dx = ix - moved[bbase + (size_t)oqi * 3 + 0];
            float dy = iy - moved[bbase + (size_t)oqi * 3 + 1];
            float dz = iz - moved[bbase + (size_t)oqi * 3 + 2];
            sqv = fmaf(dx, dx, fmaf(dy, dy, dz * dz));
        }
    }

    if (KIND == 1) {   // wave reduce -> one global atomic per wave
        float v = sqv;
#pragma unroll
        for (int sft = 1; sft < 64; sft <<= 1) v += __shfl_xor(v, sft);
        if (lane == 0) atomicAdd(outA, v * invB);
    }
}

extern "C" void kernel_launch(void* const* d_in, const int* in_sizes, int n_in,
                              void* d_out, int out_size, void* d_ws, size_t ws_size,
                              hipStream_t stream) {
    const float* src  = (const float*)d_in[0];
    const float* tgt  = (const float*)d_in[1];
    const float* flow = (const float*)d_in[2];
    float* out = (float*)d_out;

    const int B = 2;
    const int N = in_sizes[0] / (B * 3);        // 8192

    float*  curv2  = (float*)d_ws;                         // B*N*3 f32
    float*  moved  = curv2 + (size_t)B * N * 3;            // B*N*3 f32
    float4* xyzw   = (float4*)(moved + (size_t)B * N * 3); // 6*N float4
    int*    sidx   = (int*)(xyzw + (size_t)6 * N);         // 6*N int
    int*    bstart = sidx + (size_t)6 * N;                 // 6*(NCELL+1) int

    hipMemsetAsync(d_out, 0, sizeof(float), stream);

    sort_kernel<<<6, BLOCK, 0, stream>>>(src, tgt, flow, xyzw, sidx, bstart, N);

    // fused self-KNN curvatures: grid = 2 modes * B * N/32 = 1024 blocks
    knn_kernel<10, 8, 0, 96><<<2 * B * (N / 32), BLOCK, 0, stream>>>(
        src, tgt, flow, xyzw, sidx, bstart, nullptr, nullptr, curv2, moved, N, 0.f);

    // interp + loss: grid = B * N/32 = 512 blocks
    knn_kernel<5, 8, 1, 96><<<B * (N / 32), BLOCK, 0, stream>>>(
        src, tgt, flow, xyzw, sidx, bstart, curv2, moved, out, nullptr, N, 1.0f / B);
}